// Round 1
// baseline (749.197 us; speedup 1.0000x reference)
//
#include <hip/hip_runtime.h>
#include <hip/hip_bf16.h>

// RetinaNet loss (focal + smooth-L1) for B=8, A=120000, C=80, M=32.
// Memory-bound on the 307 MB classification tensor -> target ~51us roofline.

#define CLS 80
#define F4_PER_ANCHOR (CLS / 4)   // 20
#define MAXM 32

// ws layout: [0]=cls_sum(f32) [1]=reg_sum(f32) [2]=num_pos(u32) ; meta bytes at +256
#define META_OFF 256

__global__ void init_acc_kernel(float* acc) {
    acc[0] = 0.0f;
    acc[1] = 0.0f;
    ((unsigned int*)acc)[2] = 0u;
}

__global__ void anchor_kernel(const float* __restrict__ anchors,   // B*A*4
                              const float* __restrict__ ann,       // B*M*5
                              const float* __restrict__ out_reg,   // B*A*4
                              const int*   __restrict__ image_shape,
                              unsigned char* __restrict__ meta,    // B*A
                              float* __restrict__ acc,
                              int A, int M) {
    __shared__ float s_ann[MAXM * 5];
    __shared__ float s_area[MAXM];
    const int b   = blockIdx.y;
    const int tid = threadIdx.x;
    const float* annb = ann + (size_t)b * M * 5;
    if (tid < M * 5) s_ann[tid] = annb[tid];
    __syncthreads();
    if (tid < M) {
        float x1 = s_ann[tid * 5 + 0], y1 = s_ann[tid * 5 + 1];
        float x2 = s_ann[tid * 5 + 2], y2 = s_ann[tid * 5 + 3];
        s_area[tid] = (x2 - x1) * (y2 - y1);
    }
    __syncthreads();

    const int a = blockIdx.x * blockDim.x + tid;
    if (a >= A) return;

    const size_t idx = (size_t)b * A + a;
    const float4 an = ((const float4*)anchors)[idx];      // x1,y1,x2,y2
    const float area_a = (an.z - an.x) * (an.w - an.y);

    float maxiou = -1.0f;
    int best = 0;
    #pragma unroll
    for (int j = 0; j < MAXM; ++j) {
        if (j >= M) break;
        const float bx1 = s_ann[j * 5 + 0], by1 = s_ann[j * 5 + 1];
        const float bx2 = s_ann[j * 5 + 2], by2 = s_ann[j * 5 + 3];
        float iw = fminf(an.z, bx2) - fmaxf(an.x, bx1);
        iw = fmaxf(iw, 0.0f);
        float ih = fminf(an.w, by2) - fmaxf(an.y, by1);
        ih = fmaxf(ih, 0.0f);
        const float inter = iw * ih;
        const float iou = inter / fmaxf(area_a + s_area[j] - inter, 1e-8f);
        if (iou > maxiou) { maxiou = iou; best = j; }   // strict > == jnp.argmax first-max
    }

    const bool pos = (maxiou >= 0.5f);
    const bool ign = (maxiou > 0.4f) && !pos;
    const float cx = (an.x + an.z) * 0.5f;
    const float cy = (an.y + an.w) * 0.5f;
    const bool outside = (cx >= (float)image_shape[1]) || (cy >= (float)image_shape[0]);

    int state = pos ? 1 : (ign ? -1 : 0);
    if (outside) state = -1;

    unsigned char m;
    if (state == -1)      m = 0xFF;                                  // invalid: skip in cls
    else if (state == 1)  m = (unsigned char)(int)s_ann[best * 5 + 4]; // pos: class label
    else                  m = 0x80;                                  // valid negative
    meta[idx] = m;

    if (state == 1) {
        const float aw = an.z - an.x;
        const float ah = an.w - an.y;
        const float gx1 = s_ann[best * 5 + 0], gy1 = s_ann[best * 5 + 1];
        const float gx2 = s_ann[best * 5 + 2], gy2 = s_ann[best * 5 + 3];
        float t[4];
        t[0] = ((gx1 - an.x) / aw) / 0.2f;
        t[1] = ((gy1 - an.y) / ah) / 0.2f;
        t[2] = ((gx2 - an.z) / aw) / 0.2f;
        t[3] = ((gy2 - an.w) / ah) / 0.2f;
        const float4 r = ((const float4*)out_reg)[idx];
        const float rv[4] = {r.x, r.y, r.z, r.w};
        float reg = 0.0f;
        #pragma unroll
        for (int k = 0; k < 4; ++k) {
            const float d = fabsf(rv[k] - t[k]);
            // sigma^2 = 9: d < 1/9 ? 4.5 d^2 : d - 1/18
            reg += (d < (1.0f / 9.0f)) ? (4.5f * d * d) : (d - (0.5f / 9.0f));
        }
        atomicAdd(&acc[1], reg);                 // pos anchors are rare (~hundreds total)
        atomicAdd(((unsigned int*)acc) + 2, 1u);
    }
}

__device__ __forceinline__ float wave_reduce_sum(float v) {
    #pragma unroll
    for (int off = 32; off > 0; off >>= 1) v += __shfl_down(v, off, 64);
    return v;
}

__global__ void cls_kernel(const float* __restrict__ cls,        // B*A*C floats
                           const unsigned char* __restrict__ meta,
                           float* __restrict__ acc,
                           int n4) {                              // n4 = B*A*C/4
    const int i0     = blockIdx.x * blockDim.x + threadIdx.x;
    const int stride = gridDim.x * blockDim.x;
    float partial = 0.0f;

    for (int i = i0; i < n4; i += stride) {
        const int anchor = i / F4_PER_ANCHOR;        // compile-time const divisor
        const unsigned char m = meta[anchor];
        if (m == 0xFF) continue;                     // invalid anchor: no fetch, no math
        const float4 p4 = ((const float4*)cls)[i];
        const int c0 = (i - anchor * F4_PER_ANCHOR) * 4;
        const int lab = (m < 0x80) ? (int)m : -1;

        const float pv[4] = {p4.x, p4.y, p4.z, p4.w};
        #pragma unroll
        for (int k = 0; k < 4; ++k) {
            float p = fminf(fmaxf(pv[k], 1e-4f), 1.0f - 1e-4f);
            const bool is_pos = (lab == c0 + k);
            const float pt    = is_pos ? (1.0f - p) : p;
            const float alpha = is_pos ? 0.25f : 0.75f;
            // bce = -log(p) if pos else -log(1-p)  ==  -log(1 - pt)
            partial += alpha * pt * pt * (-__logf(1.0f - pt));
        }
    }

    __shared__ float red[4];
    const float w = wave_reduce_sum(partial);
    const int lane = threadIdx.x & 63;
    const int wid  = threadIdx.x >> 6;
    if (lane == 0) red[wid] = w;
    __syncthreads();
    if (threadIdx.x == 0) {
        atomicAdd(&acc[0], red[0] + red[1] + red[2] + red[3]);
    }
}

__global__ void final_kernel(const float* __restrict__ acc, float* __restrict__ out) {
    const float np   = (float)((const unsigned int*)acc)[2];
    const float norm = fmaxf(np, 1.0f);
    out[0] = (acc[0] + acc[1]) / norm;
}

extern "C" void kernel_launch(void* const* d_in, const int* in_sizes, int n_in,
                              void* d_out, int out_size, void* d_ws, size_t ws_size,
                              hipStream_t stream) {
    const float* out_reg = (const float*)d_in[0];   // B*A*4
    const float* out_cls = (const float*)d_in[1];   // B*A*C
    const float* ann     = (const float*)d_in[2];   // B*M*5
    const float* anchors = (const float*)d_in[3];   // B*A*4
    const int*   ishape  = (const int*)d_in[4];     // 2
    float* out = (float*)d_out;

    const int B = in_sizes[2] / (MAXM * 5);         // 8
    const int BA = in_sizes[0] / 4;                 // B*A
    const int A = BA / B;                           // 120000
    const int M = MAXM;                             // 32
    const int n4 = in_sizes[1] / 4;                 // B*A*C/4 = 19.2M

    float* acc = (float*)d_ws;
    unsigned char* meta = (unsigned char*)d_ws + META_OFF;

    init_acc_kernel<<<1, 1, 0, stream>>>(acc);

    dim3 g1((A + 255) / 256, B);
    anchor_kernel<<<g1, 256, 0, stream>>>(anchors, ann, out_reg, ishape, meta, acc, A, M);

    cls_kernel<<<4096, 256, 0, stream>>>(out_cls, meta, acc, n4);

    final_kernel<<<1, 1, 0, stream>>>(acc, out);
}

// Round 2
// 501.685 us; speedup vs baseline: 1.4934x; 1.4934x over previous
//
#include <hip/hip_runtime.h>
#include <hip/hip_bf16.h>

// RetinaNet loss (focal + smooth-L1) for B=8, A=120000, C=80, M=32.
// Memory-bound on the 307 MB classification tensor -> target ~51us roofline.
// R2: removed ALL same-address atomics (R1 post-mortem: anchor_kernel spent
// 315us serializing ~10k atomicAdds to 2 addresses). Per-block partials +
// final reduce kernel instead.

#define CLS 80
#define F4_PER_ANCHOR (CLS / 4)   // 20
#define MAXM 32

// ws layout (bytes):
//   [0, 960000)           meta, 1 byte per (b, anchor)
//   [960000, 975008)      reg_part   float[3752]
//   [975008, 990016)      cnt_part   float[3752]
//   [990016, 1006400)     cls_part   float[4096]
#define META_BYTES   960000
#define NBLK_ANCHOR  3752     // 469 * 8
#define NBLK_CLS     4096

__global__ void anchor_kernel(const float* __restrict__ anchors,   // B*A*4
                              const float* __restrict__ ann,       // B*M*5
                              const float* __restrict__ out_reg,   // B*A*4
                              const int*   __restrict__ image_shape,
                              unsigned char* __restrict__ meta,    // B*A
                              float* __restrict__ reg_part,        // one per block
                              float* __restrict__ cnt_part,        // one per block
                              int A, int M) {
    __shared__ float s_ann[MAXM * 5];
    __shared__ float s_area[MAXM];
    __shared__ float s_red[4][2];
    const int b   = blockIdx.y;
    const int tid = threadIdx.x;
    const float* annb = ann + (size_t)b * M * 5;
    if (tid < M * 5) s_ann[tid] = annb[tid];
    __syncthreads();
    if (tid < M) {
        float x1 = s_ann[tid * 5 + 0], y1 = s_ann[tid * 5 + 1];
        float x2 = s_ann[tid * 5 + 2], y2 = s_ann[tid * 5 + 3];
        s_area[tid] = (x2 - x1) * (y2 - y1);
    }
    __syncthreads();

    const int a = blockIdx.x * blockDim.x + tid;
    float regv = 0.0f, cntv = 0.0f;

    if (a < A) {                                   // no early return: lanes stay
        const size_t idx = (size_t)b * A + a;      // alive for the shuffle reduce
        const float4 an = ((const float4*)anchors)[idx];  // x1,y1,x2,y2
        const float area_a = (an.z - an.x) * (an.w - an.y);

        float maxiou = -1.0f;
        int best = 0;
        #pragma unroll
        for (int j = 0; j < MAXM; ++j) {
            const float bx1 = s_ann[j * 5 + 0], by1 = s_ann[j * 5 + 1];
            const float bx2 = s_ann[j * 5 + 2], by2 = s_ann[j * 5 + 3];
            float iw = fminf(an.z, bx2) - fmaxf(an.x, bx1);
            iw = fmaxf(iw, 0.0f);
            float ih = fminf(an.w, by2) - fmaxf(an.y, by1);
            ih = fmaxf(ih, 0.0f);
            const float inter = iw * ih;
            const float iou = inter / fmaxf(area_a + s_area[j] - inter, 1e-8f);
            if (iou > maxiou) { maxiou = iou; best = j; }  // strict > == jnp.argmax
        }

        const bool pos = (maxiou >= 0.5f);
        const bool ign = (maxiou > 0.4f) && !pos;
        const float cx = (an.x + an.z) * 0.5f;
        const float cy = (an.y + an.w) * 0.5f;
        const bool outside = (cx >= (float)image_shape[1]) || (cy >= (float)image_shape[0]);

        int state = pos ? 1 : (ign ? -1 : 0);
        if (outside) state = -1;

        unsigned char m;
        if (state == -1)      m = 0xFF;                                    // invalid
        else if (state == 1)  m = (unsigned char)(int)s_ann[best * 5 + 4]; // class
        else                  m = 0x80;                                    // valid neg
        meta[idx] = m;

        if (state == 1) {
            const float aw = an.z - an.x;
            const float ah = an.w - an.y;
            float t0 = ((s_ann[best * 5 + 0] - an.x) / aw) * 5.0f;  // /0.2
            float t1 = ((s_ann[best * 5 + 1] - an.y) / ah) * 5.0f;
            float t2 = ((s_ann[best * 5 + 2] - an.z) / aw) * 5.0f;
            float t3 = ((s_ann[best * 5 + 3] - an.w) / ah) * 5.0f;
            const float4 r = ((const float4*)out_reg)[idx];
            const float d0 = fabsf(r.x - t0), d1 = fabsf(r.y - t1);
            const float d2 = fabsf(r.z - t2), d3 = fabsf(r.w - t3);
            // sigma^2 = 9: d < 1/9 ? 4.5 d^2 : d - 1/18
            float reg = 0.0f;
            reg += (d0 < (1.0f/9.0f)) ? (4.5f * d0 * d0) : (d0 - (0.5f/9.0f));
            reg += (d1 < (1.0f/9.0f)) ? (4.5f * d1 * d1) : (d1 - (0.5f/9.0f));
            reg += (d2 < (1.0f/9.0f)) ? (4.5f * d2 * d2) : (d2 - (0.5f/9.0f));
            reg += (d3 < (1.0f/9.0f)) ? (4.5f * d3 * d3) : (d3 - (0.5f/9.0f));
            regv = reg;
            cntv = 1.0f;
        }
    }

    // all 64 lanes of every wave are active here
    #pragma unroll
    for (int off = 32; off > 0; off >>= 1) {
        regv += __shfl_down(regv, off, 64);
        cntv += __shfl_down(cntv, off, 64);
    }
    const int lane = tid & 63, wid = tid >> 6;
    if (lane == 0) { s_red[wid][0] = regv; s_red[wid][1] = cntv; }
    __syncthreads();
    if (tid == 0) {
        const int blk = blockIdx.y * gridDim.x + blockIdx.x;
        reg_part[blk] = s_red[0][0] + s_red[1][0] + s_red[2][0] + s_red[3][0];
        cnt_part[blk] = s_red[0][1] + s_red[1][1] + s_red[2][1] + s_red[3][1];
    }
}

__global__ void cls_kernel(const float* __restrict__ cls,        // B*A*C floats
                           const unsigned char* __restrict__ meta,
                           float* __restrict__ cls_part,         // one per block
                           int n4) {                             // n4 = B*A*C/4
    const int i0     = blockIdx.x * blockDim.x + threadIdx.x;
    const int stride = gridDim.x * blockDim.x;
    float partial = 0.0f;

    for (int i = i0; i < n4; i += stride) {
        const int anchor = i / F4_PER_ANCHOR;        // const-divisor -> mul_hi
        const unsigned char m = meta[anchor];        // L1-broadcast byte
        if (m == 0xFF) continue;                     // invalid anchor
        const float4 p4 = ((const float4*)cls)[i];
        const int c0 = (i - anchor * F4_PER_ANCHOR) * 4;
        const int lab = (m < 0x80) ? (int)m : -1;

        const float pv[4] = {p4.x, p4.y, p4.z, p4.w};
        #pragma unroll
        for (int k = 0; k < 4; ++k) {
            float p = fminf(fmaxf(pv[k], 1e-4f), 1.0f - 1e-4f);
            const bool is_pos = (lab == c0 + k);
            const float pt    = is_pos ? (1.0f - p) : p;
            const float alpha = is_pos ? 0.25f : 0.75f;
            // bce = -log(p) if pos else -log(1-p)  ==  -log(1 - pt)
            partial += alpha * pt * pt * (-__logf(1.0f - pt));
        }
    }

    __shared__ float red[4];
    #pragma unroll
    for (int off = 32; off > 0; off >>= 1) partial += __shfl_down(partial, off, 64);
    const int lane = threadIdx.x & 63;
    const int wid  = threadIdx.x >> 6;
    if (lane == 0) red[wid] = partial;
    __syncthreads();
    if (threadIdx.x == 0)
        cls_part[blockIdx.x] = red[0] + red[1] + red[2] + red[3];
}

__global__ void final_kernel(const float* __restrict__ reg_part,
                             const float* __restrict__ cnt_part,
                             const float* __restrict__ cls_part,
                             int n_anchor_blk, int n_cls_blk,
                             float* __restrict__ out) {
    float r = 0.0f, c = 0.0f, cl = 0.0f;
    for (int i = threadIdx.x; i < n_anchor_blk; i += blockDim.x) {
        r += reg_part[i];
        c += cnt_part[i];
    }
    for (int i = threadIdx.x; i < n_cls_blk; i += blockDim.x)
        cl += cls_part[i];

    #pragma unroll
    for (int off = 32; off > 0; off >>= 1) {
        r  += __shfl_down(r,  off, 64);
        c  += __shfl_down(c,  off, 64);
        cl += __shfl_down(cl, off, 64);
    }
    __shared__ float red[16][3];
    const int lane = threadIdx.x & 63, wid = threadIdx.x >> 6;
    if (lane == 0) { red[wid][0] = r; red[wid][1] = c; red[wid][2] = cl; }
    __syncthreads();
    if (threadIdx.x == 0) {
        float rs = 0.0f, cs = 0.0f, cls = 0.0f;
        const int nw = blockDim.x >> 6;
        for (int w = 0; w < nw; ++w) { rs += red[w][0]; cs += red[w][1]; cls += red[w][2]; }
        out[0] = (cls + rs) / fmaxf(cs, 1.0f);
    }
}

extern "C" void kernel_launch(void* const* d_in, const int* in_sizes, int n_in,
                              void* d_out, int out_size, void* d_ws, size_t ws_size,
                              hipStream_t stream) {
    const float* out_reg = (const float*)d_in[0];   // B*A*4
    const float* out_cls = (const float*)d_in[1];   // B*A*C
    const float* ann     = (const float*)d_in[2];   // B*M*5
    const float* anchors = (const float*)d_in[3];   // B*A*4
    const int*   ishape  = (const int*)d_in[4];     // 2
    float* out = (float*)d_out;

    const int B  = in_sizes[2] / (MAXM * 5);        // 8
    const int BA = in_sizes[0] / 4;                 // B*A
    const int A  = BA / B;                          // 120000
    const int M  = MAXM;                            // 32
    const int n4 = in_sizes[1] / 4;                 // B*A*C/4 = 19.2M

    unsigned char* meta = (unsigned char*)d_ws;
    float* reg_part = (float*)((char*)d_ws + META_BYTES);
    float* cnt_part = (float*)((char*)d_ws + META_BYTES + 15008);
    float* cls_part = (float*)((char*)d_ws + META_BYTES + 30016);

    const int gx = (A + 255) / 256;                 // 469
    dim3 g1(gx, B);
    anchor_kernel<<<g1, 256, 0, stream>>>(anchors, ann, out_reg, ishape, meta,
                                          reg_part, cnt_part, A, M);

    cls_kernel<<<NBLK_CLS, 256, 0, stream>>>(out_cls, meta, cls_part, n4);

    final_kernel<<<1, 1024, 0, stream>>>(reg_part, cnt_part, cls_part,
                                         gx * B, NBLK_CLS, out);
}

// Round 3
// 490.890 us; speedup vs baseline: 1.5262x; 1.0220x over previous
//
#include <hip/hip_runtime.h>
#include <hip/hip_bf16.h>

// RetinaNet loss (focal + smooth-L1) for B=8, A=120000, C=80, M=32.
// R3: fused anchor-assignment + focal-loss into ONE kernel (block owns 256
// anchors: phase 1 = IoU/meta into LDS, phase 2 = stream 256x20 float4s of
// cls). Division-free IoU argmax via cross-multiplication. Per-block
// partials (no same-address atomics -- R1 lesson), tiny final reduce.
// Kernel-side floor: ~322 MB mandatory traffic ~= 50 us.

#define CLS 80
#define F4_PER_ANCHOR (CLS / 4)   // 20
#define MAXM 32
#define APB 256                   // anchors per block

__global__ void __launch_bounds__(256)
fused_kernel(const float* __restrict__ anchors,   // B*A*4
             const float* __restrict__ ann,       // B*M*5
             const float* __restrict__ out_reg,   // B*A*4
             const float* __restrict__ cls,       // B*A*C
             const int*   __restrict__ image_shape,
             float* __restrict__ part,            // 3 floats per block: cls,reg,cnt
             int A) {
    __shared__ float s_ann[MAXM * 5];
    __shared__ float s_area[MAXM];
    __shared__ unsigned char s_meta[APB];
    __shared__ float s_red[4][3];

    const int b   = blockIdx.y;
    const int tid = threadIdx.x;
    const int a0  = blockIdx.x * APB;

    const float* annb = ann + (size_t)b * MAXM * 5;
    if (tid < MAXM * 5) s_ann[tid] = annb[tid];
    __syncthreads();
    if (tid < MAXM) {
        const float x1 = s_ann[tid*5+0], y1 = s_ann[tid*5+1];
        const float x2 = s_ann[tid*5+2], y2 = s_ann[tid*5+3];
        s_area[tid] = (x2 - x1) * (y2 - y1);
    }
    __syncthreads();

    // ---- phase 1: anchor assignment (one thread = one anchor) ----
    float regv = 0.0f, cntv = 0.0f;
    const int a = a0 + tid;
    if (a < A) {
        const size_t idx = (size_t)b * A + a;
        const float4 an = ((const float4*)anchors)[idx];   // x1,y1,x2,y2
        const float area_a = (an.z - an.x) * (an.w - an.y);

        // division-free argmax: iou_j > iou_best <=> inter_j*union_b > inter_b*union_j
        float inter_b = 0.0f, union_b = 1.0f;
        int best = 0;
        #pragma unroll
        for (int j = 0; j < MAXM; ++j) {
            const float bx1 = s_ann[j*5+0], by1 = s_ann[j*5+1];
            const float bx2 = s_ann[j*5+2], by2 = s_ann[j*5+3];
            const float iw = fmaxf(fminf(an.z, bx2) - fmaxf(an.x, bx1), 0.0f);
            const float ih = fmaxf(fminf(an.w, by2) - fmaxf(an.y, by1), 0.0f);
            const float inter = iw * ih;
            const float uni = fmaxf(area_a + s_area[j] - inter, 1e-8f);
            if (inter * union_b > inter_b * uni) {   // strict > == jnp.argmax first-max
                inter_b = inter; union_b = uni; best = j;
            }
        }

        const bool pos = (2.0f * inter_b >= union_b);          // iou >= 0.5
        const bool ign = (inter_b > 0.4f * union_b) && !pos;   // iou > 0.4
        const float cx = (an.x + an.z) * 0.5f;
        const float cy = (an.y + an.w) * 0.5f;
        const bool outside = (cx >= (float)image_shape[1]) || (cy >= (float)image_shape[0]);

        int state = pos ? 1 : (ign ? -1 : 0);
        if (outside) state = -1;

        unsigned char m;
        if (state == -1)      m = 0xFF;                                   // invalid
        else if (state == 1)  m = (unsigned char)(int)s_ann[best*5+4];    // class
        else                  m = 0x80;                                   // valid neg
        s_meta[tid] = m;

        if (state == 1) {   // rare (~0.5% of anchors)
            const float aw = an.z - an.x;
            const float ah = an.w - an.y;
            const float t0 = ((s_ann[best*5+0] - an.x) / aw) * 5.0f;  // /0.2
            const float t1 = ((s_ann[best*5+1] - an.y) / ah) * 5.0f;
            const float t2 = ((s_ann[best*5+2] - an.z) / aw) * 5.0f;
            const float t3 = ((s_ann[best*5+3] - an.w) / ah) * 5.0f;
            const float4 r = ((const float4*)out_reg)[idx];
            const float d0 = fabsf(r.x - t0), d1 = fabsf(r.y - t1);
            const float d2 = fabsf(r.z - t2), d3 = fabsf(r.w - t3);
            // sigma^2 = 9: d < 1/9 ? 4.5 d^2 : d - 1/18
            float reg = 0.0f;
            reg += (d0 < (1.0f/9.0f)) ? (4.5f*d0*d0) : (d0 - (0.5f/9.0f));
            reg += (d1 < (1.0f/9.0f)) ? (4.5f*d1*d1) : (d1 - (0.5f/9.0f));
            reg += (d2 < (1.0f/9.0f)) ? (4.5f*d2*d2) : (d2 - (0.5f/9.0f));
            reg += (d3 < (1.0f/9.0f)) ? (4.5f*d3*d3) : (d3 - (0.5f/9.0f));
            regv = reg;
            cntv = 1.0f;
        }
    } else {
        s_meta[tid] = 0xFF;
    }
    __syncthreads();

    // ---- phase 2: focal loss over this block's cls rows (coalesced f4) ----
    const int nA  = min(APB, A - a0);
    const int nf4 = nA * F4_PER_ANCHOR;                      // <= 5120
    const float4* cls4 = (const float4*)cls
                       + ((size_t)b * A + a0) * F4_PER_ANCHOR;
    float clsv = 0.0f;

    for (int i = tid; i < nf4; i += APB) {
        const int al = i / F4_PER_ANCHOR;                    // const-div -> mul_hi
        const unsigned char m = s_meta[al];                  // LDS broadcast
        if (m == 0xFF) continue;                             // invalid anchor
        const float4 p4 = cls4[i];
        const int c0  = (i - al * F4_PER_ANCHOR) * 4;
        const int lab = (m < 0x80) ? (int)m : -1;

        const float pv[4] = {p4.x, p4.y, p4.z, p4.w};
        #pragma unroll
        for (int k = 0; k < 4; ++k) {
            const float p  = fminf(fmaxf(pv[k], 1e-4f), 1.0f - 1e-4f);
            const bool is_pos = (lab == c0 + k);
            const float pt    = is_pos ? (1.0f - p) : p;
            const float alpha = is_pos ? 0.25f : 0.75f;
            // bce = -log(p) if pos else -log(1-p)  ==  -log(1 - pt)
            clsv += alpha * pt * pt * (-__logf(1.0f - pt));
        }
    }

    // ---- block reduce (all 64 lanes of every wave active) ----
    #pragma unroll
    for (int off = 32; off > 0; off >>= 1) {
        clsv += __shfl_down(clsv, off, 64);
        regv += __shfl_down(regv, off, 64);
        cntv += __shfl_down(cntv, off, 64);
    }
    const int lane = tid & 63, wid = tid >> 6;
    if (lane == 0) { s_red[wid][0] = clsv; s_red[wid][1] = regv; s_red[wid][2] = cntv; }
    __syncthreads();
    if (tid == 0) {
        const int blk = blockIdx.y * gridDim.x + blockIdx.x;
        part[blk*3+0] = s_red[0][0] + s_red[1][0] + s_red[2][0] + s_red[3][0];
        part[blk*3+1] = s_red[0][1] + s_red[1][1] + s_red[2][1] + s_red[3][1];
        part[blk*3+2] = s_red[0][2] + s_red[1][2] + s_red[2][2] + s_red[3][2];
    }
}

__global__ void final_kernel(const float* __restrict__ part, int n_blk,
                             float* __restrict__ out) {
    float cl = 0.0f, r = 0.0f, c = 0.0f;
    for (int i = threadIdx.x; i < n_blk; i += blockDim.x) {
        cl += part[i*3+0];
        r  += part[i*3+1];
        c  += part[i*3+2];
    }
    #pragma unroll
    for (int off = 32; off > 0; off >>= 1) {
        cl += __shfl_down(cl, off, 64);
        r  += __shfl_down(r,  off, 64);
        c  += __shfl_down(c,  off, 64);
    }
    __shared__ float red[16][3];
    const int lane = threadIdx.x & 63, wid = threadIdx.x >> 6;
    if (lane == 0) { red[wid][0] = cl; red[wid][1] = r; red[wid][2] = c; }
    __syncthreads();
    if (threadIdx.x == 0) {
        float cls = 0.0f, rs = 0.0f, cs = 0.0f;
        const int nw = blockDim.x >> 6;
        for (int w = 0; w < nw; ++w) { cls += red[w][0]; rs += red[w][1]; cs += red[w][2]; }
        out[0] = (cls + rs) / fmaxf(cs, 1.0f);
    }
}

extern "C" void kernel_launch(void* const* d_in, const int* in_sizes, int n_in,
                              void* d_out, int out_size, void* d_ws, size_t ws_size,
                              hipStream_t stream) {
    const float* out_reg = (const float*)d_in[0];   // B*A*4
    const float* out_cls = (const float*)d_in[1];   // B*A*C
    const float* ann     = (const float*)d_in[2];   // B*M*5
    const float* anchors = (const float*)d_in[3];   // B*A*4
    const int*   ishape  = (const int*)d_in[4];     // 2
    float* out = (float*)d_out;

    const int B  = in_sizes[2] / (MAXM * 5);        // 8
    const int BA = in_sizes[0] / 4;                 // B*A
    const int A  = BA / B;                          // 120000

    float* part = (float*)d_ws;                     // 3 floats per block

    const int gx = (A + APB - 1) / APB;             // 469
    dim3 g1(gx, B);
    fused_kernel<<<g1, APB, 0, stream>>>(anchors, ann, out_reg, out_cls,
                                         ishape, part, A);

    final_kernel<<<1, 1024, 0, stream>>>(part, gx * B, out);
}

// Round 4
// 439.505 us; speedup vs baseline: 1.7046x; 1.1169x over previous
//
#include <hip/hip_runtime.h>
#include <hip/hip_bf16.h>

// RetinaNet loss (focal + smooth-L1) for B=8, A=120000, C=80, M=32.
// R4: branch-free, unrolled focal phase. R3's inner loop had a data-dependent
// `continue` guarding every global_load_dwordx4 -> loads couldn't be
// batched/pipelined across iterations. Now: meta as int in LDS, invalid
// anchors contribute 0 via a multiplicative mask, loop unrolled 5x with
// unconditional independent loads. Per-block partials (R1 lesson: never
// same-address atomics), tiny final reduce.
// Kernel floor: ~322 MB mandatory traffic ~= 50 us @ 6.3 TB/s.

#define CLS 80
#define F4_PER_ANCHOR (CLS / 4)   // 20
#define MAXM 32
#define APB 256                   // anchors per block

__global__ void __launch_bounds__(256)
fused_kernel(const float* __restrict__ anchors,   // B*A*4
             const float* __restrict__ ann,       // B*M*5
             const float* __restrict__ out_reg,   // B*A*4
             const float* __restrict__ cls,       // B*A*C
             const int*   __restrict__ image_shape,
             float* __restrict__ part,            // 3 floats per block: cls,reg,cnt
             int A) {
    __shared__ float s_ann[MAXM * 5];
    __shared__ float s_area[MAXM];
    __shared__ int   s_meta[APB];    // -2 invalid, -1 valid-neg, 0..79 pos class
    __shared__ float s_red[4][3];

    const int b   = blockIdx.y;
    const int tid = threadIdx.x;
    const int a0  = blockIdx.x * APB;

    const float* annb = ann + (size_t)b * MAXM * 5;
    if (tid < MAXM * 5) s_ann[tid] = annb[tid];
    __syncthreads();
    if (tid < MAXM) {
        const float x1 = s_ann[tid*5+0], y1 = s_ann[tid*5+1];
        const float x2 = s_ann[tid*5+2], y2 = s_ann[tid*5+3];
        s_area[tid] = (x2 - x1) * (y2 - y1);
    }
    __syncthreads();

    // ---- phase 1: anchor assignment (one thread = one anchor) ----
    float regv = 0.0f, cntv = 0.0f;
    const int a = a0 + tid;
    if (a < A) {
        const size_t idx = (size_t)b * A + a;
        const float4 an = ((const float4*)anchors)[idx];   // x1,y1,x2,y2
        const float area_a = (an.z - an.x) * (an.w - an.y);

        // division-free argmax: iou_j > iou_best <=> inter_j*union_b > inter_b*union_j
        float inter_b = 0.0f, union_b = 1.0f;
        int best = 0;
        #pragma unroll
        for (int j = 0; j < MAXM; ++j) {
            const float bx1 = s_ann[j*5+0], by1 = s_ann[j*5+1];
            const float bx2 = s_ann[j*5+2], by2 = s_ann[j*5+3];
            const float iw = fmaxf(fminf(an.z, bx2) - fmaxf(an.x, bx1), 0.0f);
            const float ih = fmaxf(fminf(an.w, by2) - fmaxf(an.y, by1), 0.0f);
            const float inter = iw * ih;
            const float uni = fmaxf(area_a + s_area[j] - inter, 1e-8f);
            if (inter * union_b > inter_b * uni) {   // strict > == jnp.argmax first-max
                inter_b = inter; union_b = uni; best = j;
            }
        }

        const bool pos = (2.0f * inter_b >= union_b);          // iou >= 0.5
        const bool ign = (inter_b > 0.4f * union_b) && !pos;   // iou > 0.4
        const float cx = (an.x + an.z) * 0.5f;
        const float cy = (an.y + an.w) * 0.5f;
        const bool outside = (cx >= (float)image_shape[1]) || (cy >= (float)image_shape[0]);

        int state = pos ? 1 : (ign ? -1 : 0);
        if (outside) state = -1;

        s_meta[tid] = (state == -1) ? -2
                    : (state == 1) ? (int)s_ann[best*5+4]
                                   : -1;

        if (state == 1) {   // rare (~0.05% of anchors)
            const float aw = an.z - an.x;
            const float ah = an.w - an.y;
            const float t0 = ((s_ann[best*5+0] - an.x) / aw) * 5.0f;  // /0.2
            const float t1 = ((s_ann[best*5+1] - an.y) / ah) * 5.0f;
            const float t2 = ((s_ann[best*5+2] - an.z) / aw) * 5.0f;
            const float t3 = ((s_ann[best*5+3] - an.w) / ah) * 5.0f;
            const float4 r = ((const float4*)out_reg)[idx];
            const float d0 = fabsf(r.x - t0), d1 = fabsf(r.y - t1);
            const float d2 = fabsf(r.z - t2), d3 = fabsf(r.w - t3);
            // sigma^2 = 9: d < 1/9 ? 4.5 d^2 : d - 1/18
            float reg = 0.0f;
            reg += (d0 < (1.0f/9.0f)) ? (4.5f*d0*d0) : (d0 - (0.5f/9.0f));
            reg += (d1 < (1.0f/9.0f)) ? (4.5f*d1*d1) : (d1 - (0.5f/9.0f));
            reg += (d2 < (1.0f/9.0f)) ? (4.5f*d2*d2) : (d2 - (0.5f/9.0f));
            reg += (d3 < (1.0f/9.0f)) ? (4.5f*d3*d3) : (d3 - (0.5f/9.0f));
            regv = reg;
            cntv = 1.0f;
        }
    } else {
        s_meta[tid] = -2;
    }
    __syncthreads();

    // ---- phase 2: focal loss, branch-free (invalid anchors weighted 0) ----
    const float4* cls4 = (const float4*)cls
                       + ((size_t)b * A + a0) * F4_PER_ANCHOR;
    float clsv = 0.0f;
    const int nA = min(APB, A - a0);

    if (nA == APB) {
        // full block: exactly 20 iterations, unconditional independent loads
        #pragma unroll 5
        for (int it = 0; it < F4_PER_ANCHOR; ++it) {
            const int i  = tid + it * APB;
            const int al = i / F4_PER_ANCHOR;            // const-div -> mul_hi
            const float4 p4 = cls4[i];                   // unconditional
            const int lab = s_meta[al];                  // LDS dword broadcast
            const float valid = (lab == -2) ? 0.0f : 1.0f;
            const int c0 = (i - al * F4_PER_ANCHOR) * 4;

            const float pv[4] = {p4.x, p4.y, p4.z, p4.w};
            #pragma unroll
            for (int k = 0; k < 4; ++k) {
                const float p  = fminf(fmaxf(pv[k], 1e-4f), 1.0f - 1e-4f);
                const bool is_pos = (lab == c0 + k);     // never true for -1/-2
                const float pt    = is_pos ? (1.0f - p) : p;
                const float scale = (is_pos ? 0.25f : 0.75f) * valid;
                // bce = -log(p) if pos else -log(1-p)  ==  -log(1 - pt)
                clsv += scale * pt * pt * (-__logf(1.0f - pt));
            }
        }
    } else {
        const int nf4 = nA * F4_PER_ANCHOR;
        for (int i = tid; i < nf4; i += APB) {
            const int al = i / F4_PER_ANCHOR;
            const float4 p4 = cls4[i];
            const int lab = s_meta[al];
            const float valid = (lab == -2) ? 0.0f : 1.0f;
            const int c0 = (i - al * F4_PER_ANCHOR) * 4;

            const float pv[4] = {p4.x, p4.y, p4.z, p4.w};
            #pragma unroll
            for (int k = 0; k < 4; ++k) {
                const float p  = fminf(fmaxf(pv[k], 1e-4f), 1.0f - 1e-4f);
                const bool is_pos = (lab == c0 + k);
                const float pt    = is_pos ? (1.0f - p) : p;
                const float scale = (is_pos ? 0.25f : 0.75f) * valid;
                clsv += scale * pt * pt * (-__logf(1.0f - pt));
            }
        }
    }

    // ---- block reduce (all 64 lanes of every wave active) ----
    #pragma unroll
    for (int off = 32; off > 0; off >>= 1) {
        clsv += __shfl_down(clsv, off, 64);
        regv += __shfl_down(regv, off, 64);
        cntv += __shfl_down(cntv, off, 64);
    }
    const int lane = tid & 63, wid = tid >> 6;
    if (lane == 0) { s_red[wid][0] = clsv; s_red[wid][1] = regv; s_red[wid][2] = cntv; }
    __syncthreads();
    if (tid == 0) {
        const int blk = blockIdx.y * gridDim.x + blockIdx.x;
        part[blk*3+0] = s_red[0][0] + s_red[1][0] + s_red[2][0] + s_red[3][0];
        part[blk*3+1] = s_red[0][1] + s_red[1][1] + s_red[2][1] + s_red[3][1];
        part[blk*3+2] = s_red[0][2] + s_red[1][2] + s_red[2][2] + s_red[3][2];
    }
}

__global__ void final_kernel(const float* __restrict__ part, int n_blk,
                             float* __restrict__ out) {
    float cl = 0.0f, r = 0.0f, c = 0.0f;
    for (int i = threadIdx.x; i < n_blk; i += blockDim.x) {
        cl += part[i*3+0];
        r  += part[i*3+1];
        c  += part[i*3+2];
    }
    #pragma unroll
    for (int off = 32; off > 0; off >>= 1) {
        cl += __shfl_down(cl, off, 64);
        r  += __shfl_down(r,  off, 64);
        c  += __shfl_down(c,  off, 64);
    }
    __shared__ float red[16][3];
    const int lane = threadIdx.x & 63, wid = threadIdx.x >> 6;
    if (lane == 0) { red[wid][0] = cl; red[wid][1] = r; red[wid][2] = c; }
    __syncthreads();
    if (threadIdx.x == 0) {
        float cls = 0.0f, rs = 0.0f, cs = 0.0f;
        const int nw = blockDim.x >> 6;
        for (int w = 0; w < nw; ++w) { cls += red[w][0]; rs += red[w][1]; cs += red[w][2]; }
        out[0] = (cls + rs) / fmaxf(cs, 1.0f);
    }
}

extern "C" void kernel_launch(void* const* d_in, const int* in_sizes, int n_in,
                              void* d_out, int out_size, void* d_ws, size_t ws_size,
                              hipStream_t stream) {
    const float* out_reg = (const float*)d_in[0];   // B*A*4
    const float* out_cls = (const float*)d_in[1];   // B*A*C
    const float* ann     = (const float*)d_in[2];   // B*M*5
    const float* anchors = (const float*)d_in[3];   // B*A*4
    const int*   ishape  = (const int*)d_in[4];     // 2
    float* out = (float*)d_out;

    const int B  = in_sizes[2] / (MAXM * 5);        // 8
    const int BA = in_sizes[0] / 4;                 // B*A
    const int A  = BA / B;                          // 120000

    float* part = (float*)d_ws;                     // 3 floats per block

    const int gx = (A + APB - 1) / APB;             // 469
    dim3 g1(gx, B);
    fused_kernel<<<g1, APB, 0, stream>>>(anchors, ann, out_reg, out_cls,
                                         ishape, part, A);

    final_kernel<<<1, 1024, 0, stream>>>(part, gx * B, out);
}